// Round 1
// baseline (44.687 us; speedup 1.0000x reference)
//
#include <hip/hip_runtime.h>
#include <math.h>

// SegmentTreeAttention — MI355X (gfx950)
// B=16, S=8192, D=64, N=32, LEVELS=5. f32 in/out. valid_lens per-batch.
//
// Structure: one block handles (batch b, 128 consecutive queries).
//  - Pk/Pv prefix tables (32x64 f32 each) staged in LDS, row stride 68 dwords.
//  - 16 lanes per query, float4 per lane (64 columns).
//  - Descent frontier rows P[l-1], P[clamp(min(r,n-1))] cached in registers;
//    only P[mid] is read from LDS each level (2 x ds_read_b128 per lane).
//  - Dot reduce: 4-step __shfl_xor butterfly within the 16-lane group.

#define SEG_N   32
#define DIM     64
#define LEVELS  5
#define SPB     128     // queries per block
#define THREADS 256
#define GROUPS  16      // 16-lane query groups per block
#define PAD     68      // LDS row stride in dwords

__device__ __forceinline__ float4 seg4(bool ok, const float4 hi, const float4 lo) {
    float4 r;
    r.x = ok ? (hi.x - lo.x) : 0.0f;
    r.y = ok ? (hi.y - lo.y) : 0.0f;
    r.z = ok ? (hi.z - lo.z) : 0.0f;
    r.w = ok ? (hi.w - lo.w) : 0.0f;
    return r;
}

__device__ __forceinline__ float dot4(const float4 a, const float4 b) {
    return a.x * b.x + a.y * b.y + a.z * b.z + a.w * b.w;
}

__device__ __forceinline__ float4 sel4(bool c, const float4 a, const float4 b) {
    float4 r;
    r.x = c ? a.x : b.x;
    r.y = c ? a.y : b.y;
    r.z = c ? a.z : b.z;
    r.w = c ? a.w : b.w;
    return r;
}

__global__ __launch_bounds__(THREADS) void segtree_attn_kernel(
    const float* __restrict__ q,
    const float* __restrict__ keys,
    const float* __restrict__ values,
    const int*   __restrict__ vlen,
    float*       __restrict__ out,
    int S)
{
    __shared__ float Pk[SEG_N * PAD];
    __shared__ float Pv[SEG_N * PAD];

    const int b = blockIdx.y;
    const int t = threadIdx.x;

    // ---- Stage prefix sums into LDS: P[0]=0, P[m]=sum_{l=1..m} x[l] ----
    if (t < 2 * DIM) {
        const int col = t & (DIM - 1);
        const float* src = ((t < DIM) ? keys : values) + (size_t)b * SEG_N * DIM + col;
        float* dst = (t < DIM) ? Pk : Pv;
        float acc = 0.0f;
        dst[col] = 0.0f;
        #pragma unroll
        for (int row = 1; row < SEG_N; ++row) {
            acc += src[row * DIM];
            dst[row * PAD + col] = acc;
        }
    }
    const int n = vlen[b];          // block-uniform (valid_lens is [B])
    __syncthreads();

    const int g  = t >> 4;          // query group within block
    const int u  = t & 15;          // lane within group
    const int c4 = u * 4;           // column base (float4)

    // static row P[clamp(n-1, 0, 31)]
    const int hnc = max(min(n - 1, SEG_N - 1), 0);
    const float4 pk_n1 = *(const float4*)&Pk[hnc * PAD + c4];
    const float4 pv_n1 = *(const float4*)&Pv[hnc * PAD + c4];

    const int s0 = blockIdx.x * SPB;

    for (int it = 0; it < SPB / GROUPS; ++it) {
        const int s = s0 + it * GROUPS + g;
        const float4 qv = *(const float4*)(q + ((size_t)b * S + s) * DIM + c4);

        int l = 1, r = SEG_N;
        float4 ans = make_float4(0.f, 0.f, 0.f, 0.f);
        float4 pkA = make_float4(0.f, 0.f, 0.f, 0.f);   // Pk[l-1], l=1 -> row 0 = zeros
        float4 pvA = make_float4(0.f, 0.f, 0.f, 0.f);
        float4 pkR = pk_n1;   // Pk[clamp(min(r,n-1),0,31)], r=32 -> row hnc
        float4 pvR = pv_n1;

        #pragma unroll
        for (int lev = 0; lev < LEVELS; ++lev) {
            const int mid = (l + r) >> 1;
            const float4 pkM = *(const float4*)&Pk[mid * PAD + c4];
            const float4 pvM = *(const float4*)&Pv[mid * PAD + c4];

            const bool inL  = (mid <= n - 1);           // hiL row == mid ?
            const float4 pkHiL = sel4(inL, pkM, pk_n1); // Pk[clamp(min(mid,n-1),0,31)]
            const float4 pvHiL = sel4(inL, pvM, pv_n1);
            const bool okL = (min(mid, n - 1) >= l);
            const bool okR = (min(r,   n - 1) >= mid + 1);

            const float4 kL = seg4(okL, pkHiL, pkA);
            const float4 kR = seg4(okR, pkR,   pkM);

            float sL = dot4(qv, kL);
            float sR = dot4(qv, kR);
            #pragma unroll
            for (int m = 1; m < 16; m <<= 1) {
                sL += __shfl_xor(sL, m, 64);
                sR += __shfl_xor(sR, m, 64);
            }
            const float ls = 1.0f / (1.0f + __expf(-sL));
            const float rs = 1.0f / (1.0f + __expf(-sR));
            const bool cond = (ls >= rs);               // group-uniform

            const float4 vL = seg4(okL, pvHiL, pvA);
            const float4 vR = seg4(okR, pvR,   pvM);

            float4 add;
            add.x = cond ? (vR.x * rs) : (vL.x * ls);
            add.y = cond ? (vR.y * rs) : (vL.y * ls);
            add.z = cond ? (vR.z * rs) : (vL.z * ls);
            add.w = cond ? (vR.w * rs) : (vL.w * ls);

            ans.x = ans.x * 0.5f + add.x;
            ans.y = ans.y * 0.5f + add.y;
            ans.z = ans.z * 0.5f + add.z;
            ans.w = ans.w * 0.5f + add.w;

            if (cond) {
                r = mid;
                pkR = pkHiL; pvR = pvHiL;
            } else {
                l = mid + 1;
                pkA = pkM;  pvA = pvM;
            }
        }

        *(float4*)(out + ((size_t)b * S + s) * DIM + c4) = ans;
    }
}

extern "C" void kernel_launch(void* const* d_in, const int* in_sizes, int n_in,
                              void* d_out, int out_size, void* d_ws, size_t ws_size,
                              hipStream_t stream) {
    const float* q    = (const float*)d_in[0];
    const float* keys = (const float*)d_in[1];
    const float* vals = (const float*)d_in[2];
    const int*   vl   = (const int*)d_in[3];
    float* out = (float*)d_out;

    const int B = in_sizes[3];                 // 16
    const int S = in_sizes[0] / (B * DIM);     // 8192

    dim3 grid(S / SPB, B);
    segtree_attn_kernel<<<grid, THREADS, 0, stream>>>(q, keys, vals, vl, out, S);
}

// Round 2
// 30.356 us; speedup vs baseline: 1.4721x; 1.4721x over previous
//
#include <hip/hip_runtime.h>
#include <math.h>

// SegmentTreeAttention — MI355X (gfx950), round 2.
// B=16, S=8192, D=64, N=32, LEVELS=5. f32 in/out. valid_lens per-batch.
//
// Changes vs round 1 (49 us, VALU/latency-bound at 13% HBM):
//  - 8 lanes per query (2x float4 per lane) -> group-uniform ops amortize
//    over 8 queries/wave; shuffle reduce is 3 steps not 4.
//  - ok-masks + 0.5^k level scale folded into ONE scalar weight per level
//    (exact pow2 scale => value math bit-compatible with reference).
//  - Value accumulation deferred out of the descent loop: record
//    (w, hiRow, loRow) per level, gather Pv rows afterwards (off the
//    serial reduce->sigmoid->cond chain; frees loop VGPRs).
//  - 2 independent queries per group walk the level loop together (ILP-2).
// Numerics: identical sigmoid formula (IEEE div + __expf) and
// subtract-then-dot segment construction as the passing round-1 kernel.

#define SEG_N   32
#define DIM     64
#define LEVELS  5
#define QPB     128     // queries per block
#define THREADS 256
#define PAD     68      // LDS row stride in dwords

__device__ __forceinline__ float4 f4sub(const float4 a, const float4 b) {
    return make_float4(a.x - b.x, a.y - b.y, a.z - b.z, a.w - b.w);
}
__device__ __forceinline__ float4 sel4(bool c, const float4 a, const float4 b) {
    return make_float4(c ? a.x : b.x, c ? a.y : b.y, c ? a.z : b.z, c ? a.w : b.w);
}
__device__ __forceinline__ float dot4(const float4 a, const float4 b) {
    return a.x * b.x + a.y * b.y + a.z * b.z + a.w * b.w;
}
__device__ __forceinline__ void fma4(float4& acc, const float4 hi, const float4 lo, float w) {
    acc.x = fmaf(hi.x - lo.x, w, acc.x);
    acc.y = fmaf(hi.y - lo.y, w, acc.y);
    acc.z = fmaf(hi.z - lo.z, w, acc.z);
    acc.w = fmaf(hi.w - lo.w, w, acc.w);
}

__global__ __launch_bounds__(THREADS) void segtree_attn_kernel(
    const float* __restrict__ q,
    const float* __restrict__ keys,
    const float* __restrict__ values,
    const int*   __restrict__ vlen,
    float*       __restrict__ out,
    int S)
{
    __shared__ float Pk[SEG_N * PAD];
    __shared__ float Pv[SEG_N * PAD];

    const int b = blockIdx.y;
    const int t = threadIdx.x;

    // ---- Stage prefix sums into LDS: P[0]=0, P[m]=sum_{l=1..m} x[l] ----
    if (t < 2 * DIM) {
        const int col = t & (DIM - 1);
        const float* src = ((t < DIM) ? keys : values) + (size_t)b * SEG_N * DIM + col;
        float* dst = (t < DIM) ? Pk : Pv;
        float acc = 0.0f;
        dst[col] = 0.0f;
        #pragma unroll
        for (int row = 1; row < SEG_N; ++row) {
            acc += src[row * DIM];
            dst[row * PAD + col] = acc;
        }
    }
    const int n = vlen[b];          // block-uniform (valid_lens is [B])
    __syncthreads();

    const int g = t >> 3;           // query group within block (0..31)
    const int u = t & 7;            // lane within group
    const int c = u * 8;            // column base (2x float4)

    const int hnc = max(min(n - 1, SEG_N - 1), 0);
    const float4 pkN0 = *(const float4*)&Pk[hnc * PAD + c];
    const float4 pkN1 = *(const float4*)&Pk[hnc * PAD + c + 4];

    const int s0 = blockIdx.x * QPB;
    const float scale[LEVELS] = {0.0625f, 0.125f, 0.25f, 0.5f, 1.0f};

    for (int it = 0; it < QPB / 64; ++it) {
        const int sA = s0 + it * 64 + g;
        const int sB = sA + 32;

        const float* qpA = q + ((size_t)b * S + sA) * DIM + c;
        const float* qpB = q + ((size_t)b * S + sB) * DIM + c;
        const float4 qA0 = *(const float4*)qpA;
        const float4 qA1 = *(const float4*)(qpA + 4);
        const float4 qB0 = *(const float4*)qpB;
        const float4 qB1 = *(const float4*)(qpB + 4);

        int lA = 1, rA = SEG_N, rowA_A = 0, rowR_A = hnc;
        int lB = 1, rB = SEG_N, rowA_B = 0, rowR_B = hnc;
        float4 pkA_A0 = make_float4(0.f,0.f,0.f,0.f), pkA_A1 = make_float4(0.f,0.f,0.f,0.f);
        float4 pkA_B0 = make_float4(0.f,0.f,0.f,0.f), pkA_B1 = make_float4(0.f,0.f,0.f,0.f);
        float4 pkR_A0 = pkN0, pkR_A1 = pkN1;
        float4 pkR_B0 = pkN0, pkR_B1 = pkN1;

        float wA[LEVELS], wB[LEVELS];
        int   hiA[LEVELS], loA[LEVELS], hiB[LEVELS], loB[LEVELS];

        #pragma unroll
        for (int lev = 0; lev < LEVELS; ++lev) {
            const int midA = (lA + rA) >> 1;
            const int midB = (lB + rB) >> 1;

            const float4 pkM_A0 = *(const float4*)&Pk[midA * PAD + c];
            const float4 pkM_A1 = *(const float4*)&Pk[midA * PAD + c + 4];
            const float4 pkM_B0 = *(const float4*)&Pk[midB * PAD + c];
            const float4 pkM_B1 = *(const float4*)&Pk[midB * PAD + c + 4];

            const bool inLA = (midA <= n - 1);
            const bool inLB = (midB <= n - 1);
            const int rowHiL_A = inLA ? midA : hnc;
            const int rowHiL_B = inLB ? midB : hnc;
            const float4 pkHiL_A0 = sel4(inLA, pkM_A0, pkN0);
            const float4 pkHiL_A1 = sel4(inLA, pkM_A1, pkN1);
            const float4 pkHiL_B0 = sel4(inLB, pkM_B0, pkN0);
            const float4 pkHiL_B1 = sel4(inLB, pkM_B1, pkN1);

            // subtract-then-dot (matches reference rounding structure)
            float dLA = dot4(qA0, f4sub(pkHiL_A0, pkA_A0)) + dot4(qA1, f4sub(pkHiL_A1, pkA_A1));
            float dRA = dot4(qA0, f4sub(pkR_A0,  pkM_A0)) + dot4(qA1, f4sub(pkR_A1,  pkM_A1));
            float dLB = dot4(qB0, f4sub(pkHiL_B0, pkA_B0)) + dot4(qB1, f4sub(pkHiL_B1, pkA_B1));
            float dRB = dot4(qB0, f4sub(pkR_B0,  pkM_B0)) + dot4(qB1, f4sub(pkR_B1,  pkM_B1));

            #pragma unroll
            for (int m = 1; m < 8; m <<= 1) {
                dLA += __shfl_xor(dLA, m, 64);
                dRA += __shfl_xor(dRA, m, 64);
                dLB += __shfl_xor(dLB, m, 64);
                dRB += __shfl_xor(dRB, m, 64);
            }

            const bool okLA = (min(midA, n - 1) >= lA);
            const bool okRA = (min(rA,   n - 1) >= midA + 1);
            const bool okLB = (min(midB, n - 1) >= lB);
            const bool okRB = (min(rB,   n - 1) >= midB + 1);

            const float sLA = okLA ? dLA : 0.0f;
            const float sRA = okRA ? dRA : 0.0f;
            const float sLB = okLB ? dLB : 0.0f;
            const float sRB = okRB ? dRB : 0.0f;

            // exact formula from the passing round-1 kernel (IEEE div)
            const float lsA = 1.0f / (1.0f + __expf(-sLA));
            const float rsA = 1.0f / (1.0f + __expf(-sRA));
            const float lsB = 1.0f / (1.0f + __expf(-sLB));
            const float rsB = 1.0f / (1.0f + __expf(-sRB));

            const bool condA = (lsA >= rsA);
            const bool condB = (lsB >= rsB);

            const bool  okselA = condA ? okRA : okLA;
            const bool  okselB = condB ? okRB : okLB;
            const float wselA  = condA ? rsA : lsA;
            const float wselB  = condB ? rsB : lsB;
            wA[lev] = okselA ? (wselA * scale[lev]) : 0.0f;   // pow2 scale: exact
            wB[lev] = okselB ? (wselB * scale[lev]) : 0.0f;
            hiA[lev] = condA ? rowR_A : rowHiL_A;
            loA[lev] = condA ? midA   : rowA_A;
            hiB[lev] = condB ? rowR_B : rowHiL_B;
            loB[lev] = condB ? midB   : rowA_B;

            if (condA) {
                rA = midA; rowR_A = rowHiL_A;
                pkR_A0 = pkHiL_A0; pkR_A1 = pkHiL_A1;
            } else {
                lA = midA + 1; rowA_A = midA;
                pkA_A0 = pkM_A0; pkA_A1 = pkM_A1;
            }
            if (condB) {
                rB = midB; rowR_B = rowHiL_B;
                pkR_B0 = pkHiL_B0; pkR_B1 = pkHiL_B1;
            } else {
                lB = midB + 1; rowA_B = midB;
                pkA_B0 = pkM_B0; pkA_B1 = pkM_B1;
            }
        }

        // ---- deferred value gather: ans = sum_lev w * (Pv[hi] - Pv[lo]) ----
        float4 aA0 = make_float4(0.f,0.f,0.f,0.f), aA1 = make_float4(0.f,0.f,0.f,0.f);
        float4 aB0 = make_float4(0.f,0.f,0.f,0.f), aB1 = make_float4(0.f,0.f,0.f,0.f);
        #pragma unroll
        for (int lev = 0; lev < LEVELS; ++lev) {
            const float4 hA0 = *(const float4*)&Pv[hiA[lev] * PAD + c];
            const float4 hA1 = *(const float4*)&Pv[hiA[lev] * PAD + c + 4];
            const float4 lA0 = *(const float4*)&Pv[loA[lev] * PAD + c];
            const float4 lA1 = *(const float4*)&Pv[loA[lev] * PAD + c + 4];
            fma4(aA0, hA0, lA0, wA[lev]);
            fma4(aA1, hA1, lA1, wA[lev]);
            const float4 hB0 = *(const float4*)&Pv[hiB[lev] * PAD + c];
            const float4 hB1 = *(const float4*)&Pv[hiB[lev] * PAD + c + 4];
            const float4 lB0 = *(const float4*)&Pv[loB[lev] * PAD + c];
            const float4 lB1 = *(const float4*)&Pv[loB[lev] * PAD + c + 4];
            fma4(aB0, hB0, lB0, wB[lev]);
            fma4(aB1, hB1, lB1, wB[lev]);
        }

        float* opA = out + ((size_t)b * S + sA) * DIM + c;
        float* opB = out + ((size_t)b * S + sB) * DIM + c;
        *(float4*)opA       = aA0;
        *(float4*)(opA + 4) = aA1;
        *(float4*)opB       = aB0;
        *(float4*)(opB + 4) = aB1;
    }
}

extern "C" void kernel_launch(void* const* d_in, const int* in_sizes, int n_in,
                              void* d_out, int out_size, void* d_ws, size_t ws_size,
                              hipStream_t stream) {
    const float* q    = (const float*)d_in[0];
    const float* keys = (const float*)d_in[1];
    const float* vals = (const float*)d_in[2];
    const int*   vl   = (const int*)d_in[3];
    float* out = (float*)d_out;

    const int B = in_sizes[3];                 // 16
    const int S = in_sizes[0] / (B * DIM);     // 8192

    dim3 grid(S / QPB, B);
    segtree_attn_kernel<<<grid, THREADS, 0, stream>>>(q, keys, vals, vl, out, S);
}